// Round 3
// baseline (96.925 us; speedup 1.0000x reference)
//
#include <hip/hip_runtime.h>
#include <hip/hip_fp16.h>

// Problem constants (from reference setup_inputs)
#define N_TOK 512    // tokens (GEMM M)
#define IN_F  2048   // in_features (GEMM K)
#define OUT_F 2048   // out_features (GEMM N)
#define NNZ_ROW 128  // nnz per W row (uniform, 12.5% dense)

// GEMM tiling
#define BM 64
#define BN 64
#define BK 64
#define KT (IN_F / BK)   // 32 K-steps

typedef __attribute__((ext_vector_type(8))) _Float16 f16x8;  // MFMA A/B frag (4 VGPR)
typedef __attribute__((ext_vector_type(4))) float    f32x4;  // MFMA C/D frag

// Dense staging buffers (device globals; L2/MALL-resident working set)
__device__ __half g_xA[N_TOK * IN_F];    // A  [M=512][K=2048] fp16 row-major, 2 MB
__device__ __half g_Wd[OUT_F * IN_F];    // B^T[N=2048][K=2048] fp16 row-major, 8 MB

// ---------------------------------------------------------------------------
// Kernel 1: pack x f32 -> fp16 row-major (no transpose needed for GEMM).
// 1024 blocks x 256 thr, one float4 per thread. ~0.7 us.
// ---------------------------------------------------------------------------
__global__ __launch_bounds__(256) void pack_x(const float* __restrict__ x) {
    const int i = blockIdx.x * 256 + threadIdx.x;        // float4 id (262144)
    const float4 v = ((const float4*)x)[i];
    __half2* o = (__half2*)g_xA;
    o[2 * i + 0] = __floats2half2_rn(v.x, v.y);
    o[2 * i + 1] = __floats2half2_rn(v.z, v.w);
}

// ---------------------------------------------------------------------------
// Kernel 2: densify W. 4 rows/block; zero a f32 LDS tile, scatter-ADD the
// CSR entries (LDS atomics -> duplicate columns sum, matching reference
// segment_sum semantics), then write fp16 rows coalesced. 512 blocks. ~1.5 us.
// ---------------------------------------------------------------------------
#define DR 4
__global__ __launch_bounds__(256) void densify(const float* __restrict__ data,
                                               const int*   __restrict__ indices,
                                               const int*   __restrict__ indptr) {
    __shared__ float s_acc[DR][IN_F];                    // 32 KB
    const int r0 = blockIdx.x * DR;
    const int t  = threadIdx.x;

#pragma unroll
    for (int i = 0; i < (DR * IN_F) / (256 * 4); ++i)    // 8 iters
        ((float4*)&s_acc[0][0])[t + i * 256] = make_float4(0.f, 0.f, 0.f, 0.f);
    __syncthreads();

#pragma unroll
    for (int i = 0; i < (DR * NNZ_ROW) / 256; ++i) {     // 2 iters, coalesced nnz read
        const int g  = t + i * 256;
        const int rl = g >> 7;
        const int k  = indptr[r0 + rl] + (g & (NNZ_ROW - 1));
        atomicAdd(&s_acc[rl][indices[k]], data[k]);      // LDS atomic: dups sum
    }
    __syncthreads();

#pragma unroll
    for (int i = 0; i < (DR * IN_F) / (256 * 2); ++i) {  // 16 iters, half2 stores
        const int g  = t + i * 256;
        const int rl = g >> 10;                          // IN_F/2 = 1024 half2/row
        const int c2 = g & 1023;
        ((__half2*)&g_Wd[(size_t)(r0 + rl) * IN_F])[c2] =
            __floats2half2_rn(s_acc[rl][2 * c2], s_acc[rl][2 * c2 + 1]);
    }
}

// ---------------------------------------------------------------------------
// Kernel 3: y = xA * Wd^T via mfma_f32_16x16x32_f16.
// 64x64 tile, BK=64, 4 waves (2Mx2N, wave tile 32x32, acc 2x2 frags).
// m97-proven 2-phase double-buffer: STAGE(next) -> ds_read+MFMA(cur) ->
// barrier (compiler drains vmcnt). T2 swizzle via rule 21: LDS dest linear,
// global source XOR'd, ds_read XOR'd (involution) -> 2-way max on b128 reads.
// Grid 32x16? No: (OUT_F/BN=32, N_TOK/BM=8) = 256 blocks -> 1/CU.
// Default XCD round-robin puts 4 N-panels (1 MB) + A (2 MB) per XCD L2.
// ---------------------------------------------------------------------------
__global__ __launch_bounds__(256) void gemm_f16(float* __restrict__ y) {
    const int nt = blockIdx.x;           // N-tile 0..31
    const int mt = blockIdx.y;           // M-tile 0..7
    const int m0 = mt * BM, n0 = nt * BN;
    const int t  = threadIdx.x;
    const int w  = t >> 6, l = t & 63;
    const int fr = l & 15, fq = l >> 4;  // MFMA lane decomposition
    const int wm = w >> 1, wn = w & 1;   // wave grid 2M x 2N

    __shared__ __half Ab[2][BM * BK];    // 8 KB per buf
    __shared__ __half Bb[2][BN * BK];

    const char* Ag = (const char*)g_xA + (size_t)m0 * (IN_F * 2);
    const char* Bg = (const char*)g_Wd + (size_t)n0 * (IN_F * 2);

    // Stage one 64x64 fp16 tile pair. LDS dest = linear thread offset
    // (wave-uniform base + lane*16). Source column-bytes XOR'd with
    // (row&7)<<4 so a swizzled ds_read returns the true value (rule 21).
    auto STAGE = [&](int buf, int kt_) {
        const int kbb = kt_ * (BK * 2);
#pragma unroll
        for (int j = 0; j < 2; ++j) {
            const int off = (t + j * 256) * 16;          // 0..8191
            const int row = off >> 7;                    // tile row (128 B/row)
            const int scb = (off & 127) ^ ((row & 7) << 4);
            __builtin_amdgcn_global_load_lds(
                (const unsigned*)(Ag + row * (IN_F * 2) + kbb + scb),
                (unsigned*)((char*)&Ab[buf][0] + off), 16, 0, 0);
            __builtin_amdgcn_global_load_lds(
                (const unsigned*)(Bg + row * (IN_F * 2) + kbb + scb),
                (unsigned*)((char*)&Bb[buf][0] + off), 16, 0, 0);
        }
    };

    // Fragment byte offsets (swizzled), static per lane.
    // A row = wm*32 + mr*16 + fr, k-bytes = ks*64 + fq*16; row&7 == fr&7.
    int aoff[2][2], boff[2][2];
#pragma unroll
    for (int r = 0; r < 2; ++r)
#pragma unroll
        for (int ks = 0; ks < 2; ++ks) {
            const int cb = (ks * 64 + fq * 16) ^ ((fr & 7) << 4);
            aoff[r][ks] = (wm * 32 + r * 16 + fr) * 128 + cb;
            boff[r][ks] = (wn * 32 + r * 16 + fr) * 128 + cb;
        }

    f32x4 acc[2][2];
#pragma unroll
    for (int i = 0; i < 2; ++i)
#pragma unroll
        for (int j = 0; j < 2; ++j)
            acc[i][j] = (f32x4){0.f, 0.f, 0.f, 0.f};

    STAGE(0, 0);
    __syncthreads();                     // vmcnt(0) drain: buf0 ready
    int cur = 0;
    for (int kt = 0; kt < KT; ++kt) {
        if (kt + 1 < KT) STAGE(cur ^ 1, kt + 1);   // prefetch next tile
        f16x8 a[2][2], b[2][2];
#pragma unroll
        for (int r = 0; r < 2; ++r)
#pragma unroll
            for (int ks = 0; ks < 2; ++ks) {
                a[r][ks] = *(const f16x8*)((const char*)&Ab[cur][0] + aoff[r][ks]);
                b[r][ks] = *(const f16x8*)((const char*)&Bb[cur][0] + boff[r][ks]);
            }
#pragma unroll
        for (int mr = 0; mr < 2; ++mr)
#pragma unroll
            for (int nr = 0; nr < 2; ++nr)
#pragma unroll
                for (int ks = 0; ks < 2; ++ks)
                    acc[mr][nr] = __builtin_amdgcn_mfma_f32_16x16x32_f16(
                        a[mr][ks], b[nr][ks], acc[mr][nr], 0, 0, 0);
        __syncthreads();                 // all waves done with cur; next ready
        cur ^= 1;
    }

    // C/D layout (m89-verified, dtype-independent): row = fq*4+j, col = fr.
    float* yb = y + (size_t)m0 * OUT_F + n0;
#pragma unroll
    for (int mr = 0; mr < 2; ++mr)
#pragma unroll
        for (int nr = 0; nr < 2; ++nr)
#pragma unroll
            for (int j = 0; j < 4; ++j)
                yb[(size_t)(wm * 32 + mr * 16 + fq * 4 + j) * OUT_F +
                   (wn * 32 + nr * 16 + fr)] = acc[mr][nr][j];
}

// ---------------------------------------------------------------------------
extern "C" void kernel_launch(void* const* d_in, const int* in_sizes, int n_in,
                              void* d_out, int out_size, void* d_ws, size_t ws_size,
                              hipStream_t stream) {
    const float* x       = (const float*)d_in[0];   // [512, 2048] f32
    const float* data    = (const float*)d_in[1];   // [262144] f32
    const int*   indices = (const int*)  d_in[2];   // [262144] i32
    const int*   indptr  = (const int*)  d_in[3];   // [2049] i32
    float*       y       = (float*)d_out;           // [512, 2048] f32

    pack_x<<<dim3((N_TOK * IN_F) / (4 * 256)), 256, 0, stream>>>(x);      // 1024 blocks
    densify<<<dim3(OUT_F / DR), 256, 0, stream>>>(data, indices, indptr); // 512 blocks
    gemm_f16<<<dim3(OUT_F / BN, N_TOK / BM), 256, 0, stream>>>(y);        // 256 blocks
}

// Round 4
// 79.412 us; speedup vs baseline: 1.2205x; 1.2205x over previous
//
#include <hip/hip_runtime.h>

// Problem constants (from reference setup_inputs)
#define N_TOK 512    // tokens
#define IN_F  2048   // in_features
#define OUT_F 2048   // out_features
#define NNZ_ROW 128  // nnz per W row (uniform)

// x re-tiling: g_xt[tile][col][tok8] bf16
#define TTOK 8                    // tokens per x-tile
#define NTILE (N_TOK / TTOK)      // 64 tiles

// spmm blocking: 64 rows x 32 tokens per block
#define ROWS 64                   // W rows per block
#define TPB  32                   // tokens per block
#define TILES_PB (TPB / TTOK)     // 4 x-tiles per block
#define WPITCH 132                // dwords/row in s_w (128+4: 16B-aligned rows, bank spread)
#define YPITCH 36                 // f32/row in s_y (32+4: 16B-aligned rows)

// LDS carve (bytes)
#define SW_BYTES (ROWS * WPITCH * 4)          // 33792
#define SX_BYTES (IN_F * TTOK * 2)            // 32768
#define SY_BYTES (ROWS * YPITCH * 4)          // 9216
#define SMEM_BYTES (SW_BYTES + SX_BYTES + SY_BYTES)  // 75776 -> 2 blocks/CU (151KB<=160KB)

__device__ ushort g_xt[NTILE * IN_F * TTOK];  // 2 MB, L2-resident per XCD

static __device__ __forceinline__ unsigned f2bf(float f) {
    unsigned u = __float_as_uint(f);
    return (u + 0x7fffu + ((u >> 16) & 1u)) >> 16;
}

// ---------------------------------------------------------------------------
// Kernel 1: tile+pack x [512 tok][2048 col] f32 -> g_xt[64][2048][8] bf16.
// Reads: per j, 64 lanes hit consecutive cols = 1 KB coalesced. Writes:
// uint4 per (tile,col), lanes consecutive -> coalesced. ~1.5 us.
// ---------------------------------------------------------------------------
__global__ __launch_bounds__(256) void tile_x(const float* __restrict__ x) {
    const int tile = blockIdx.y;                      // 0..63
    const int c    = blockIdx.x * 256 + threadIdx.x;  // 0..2047
    unsigned o[4];
#pragma unroll
    for (int j = 0; j < 4; ++j) {
        const float a = x[(tile * TTOK + 2 * j    ) * IN_F + c];
        const float b = x[(tile * TTOK + 2 * j + 1) * IN_F + c];
        o[j] = f2bf(a) | (f2bf(b) << 16);
    }
    ((uint4*)g_xt)[tile * IN_F + c] = make_uint4(o[0], o[1], o[2], o[3]);
}

// ---------------------------------------------------------------------------
// Kernel 2: LDS-gather SpMM. Block = 64 rows x 32 tokens; grid 32x16 = 512
// blocks = 2/CU (2 waves/SIMD). All global reads are SEQUENTIAL:
//   - weights: one contiguous 64 KB CSR segment, packed to u32
//     (w_mantissa_masked | col) -> 33 KB LDS, pitch-132 bank spread
//   - x: per tile one LINEAR 32 KB global_load_lds memcpy (stream path)
// The random gather happens in LDS (ds_read_b64, ~2-3 cy class).
// Lane = (row 16/wave, token-quad, k-parity); k-parity halves combined by
// one shfl_xor at tile end. Output staged in LDS, stored as 256 B runs.
// ---------------------------------------------------------------------------
__global__ __launch_bounds__(256, 2) void spmm(const float* __restrict__ data,
                                               const int*   __restrict__ indices,
                                               const int*   __restrict__ indptr,
                                               float*       __restrict__ y) {
    extern __shared__ unsigned smem[];
    unsigned* s_w = smem;                                   // [ROWS][WPITCH] u32
    ushort*   s_x = (ushort*)((char*)smem + SW_BYTES);      // [IN_F][TTOK] bf16
    float*    s_y = (float*)((char*)smem + SW_BYTES + SX_BYTES); // [ROWS][YPITCH]

    const int rg = blockIdx.x;   // 0..31 row-group
    const int tb = blockIdx.y;   // 0..15 token-block
    const int r0 = rg * ROWS;
    const int t  = threadIdx.x;

    // ---- stage weights: rows r0..r0+63 are contiguous in CSR (indptr
    // monotone; 128 nnz/row per problem spec). Pack col into the 11
    // mantissa LSBs of the f32 weight (rel err <= 2^-12, << bf16's 2^-8).
    const int base0 = indptr[r0];
    const int4*   I4 = (const int4*)(indices + base0);
    const float4* D4 = (const float4*)(data + base0);
#pragma unroll
    for (int i = 0; i < (ROWS * NNZ_ROW / 4) / 256; ++i) {   // 8 iters
        const int    e  = t + i * 256;        // entry-quad 0..2047
        const int4   ci = I4[e];
        const float4 dv = D4[e];
        const int    r  = e >> 5;             // 32 quads per row
        const int    k0 = (e & 31) * 4;
        unsigned* dst = &s_w[r * WPITCH + k0];
        dst[0] = (__float_as_uint(dv.x) & 0xFFFFF800u) | (unsigned)ci.x;
        dst[1] = (__float_as_uint(dv.y) & 0xFFFFF800u) | (unsigned)ci.y;
        dst[2] = (__float_as_uint(dv.z) & 0xFFFFF800u) | (unsigned)ci.z;
        dst[3] = (__float_as_uint(dv.w) & 0xFFFFF800u) | (unsigned)ci.w;
    }

    const int l  = t & 63;
    const int w  = t >> 6;
    const int rw = w * 16 + (l >> 2);        // local row (16 rows/wave)
    const int q  = (l >> 1) & 1;             // token-quad within tile (4 tok)
    const int kh = l & 1;                    // k parity
    const unsigned* wrow = &s_w[rw * WPITCH];
    const uint2* sx2 = (const uint2*)s_x;    // [col][2 quads] (8 B = 4 bf16 tok)

    for (int ti = 0; ti < TILES_PB; ++ti) {
        // ---- stage x-tile: linear 32 KB memcpy, wave-linear LDS dest ----
        const char* src = (const char*)g_xt +
                          (size_t)(tb * TILES_PB + ti) * SX_BYTES;
#pragma unroll
        for (int i = 0; i < (SX_BYTES / 16) / 256; ++i) {    // 8 iters
            const int off = (t + i * 256) * 16;
            __builtin_amdgcn_global_load_lds((const unsigned*)(src + off),
                                             (unsigned*)((char*)s_x + off),
                                             16, 0, 0);
        }
        __syncthreads();   // drains vmcnt -> tile ready (covers w-stage @ti=0)

        float4 acc = make_float4(0.f, 0.f, 0.f, 0.f);
#pragma unroll 8
        for (int j = 0; j < NNZ_ROW / 2; ++j) {
            const unsigned u  = wrow[2 * j + kh];            // ds_read_b32
            const float    wt = __uint_as_float(u & 0xFFFFF800u);
            const uint2    xv = sx2[(u & 2047u) * 2 + q];    // ds_read_b64 gather
            acc.x += wt * __uint_as_float(xv.x << 16);  // tok 4q   (low bf16)
            acc.y += wt * __uint_as_float(xv.x);        // tok 4q+1 (high bf16+eps)
            acc.z += wt * __uint_as_float(xv.y << 16);  // tok 4q+2
            acc.w += wt * __uint_as_float(xv.y);        // tok 4q+3
        }
        // combine k-parity halves (lane pairs kh=0/1)
        acc.x += __shfl_xor(acc.x, 1);
        acc.y += __shfl_xor(acc.y, 1);
        acc.z += __shfl_xor(acc.z, 1);
        acc.w += __shfl_xor(acc.w, 1);
        if (kh == 0)   // 16B-aligned b128 write, bank-spread via YPITCH
            *(float4*)&s_y[rw * YPITCH + ti * TTOK + q * 4] = acc;
        __syncthreads();   // protect s_x overwrite / s_y completeness
    }

    // ---- epilogue: token n gets rows r0..r0+63 as 256 B coalesced runs ----
    const int n  = t >> 3;        // 0..31
    const int rb = t & 7;         // 0..7
    float v[8];
#pragma unroll
    for (int j = 0; j < 8; ++j) v[j] = s_y[(rb * 8 + j) * YPITCH + n];
    float* yp = &y[(size_t)(tb * TPB + n) * OUT_F + r0 + rb * 8];
    *(float4*)yp       = make_float4(v[0], v[1], v[2], v[3]);
    *((float4*)yp + 1) = make_float4(v[4], v[5], v[6], v[7]);
}

// ---------------------------------------------------------------------------
extern "C" void kernel_launch(void* const* d_in, const int* in_sizes, int n_in,
                              void* d_out, int out_size, void* d_ws, size_t ws_size,
                              hipStream_t stream) {
    const float* x       = (const float*)d_in[0];   // [512, 2048] f32
    const float* data    = (const float*)d_in[1];   // [262144] f32
    const int*   indices = (const int*)  d_in[2];   // [262144] i32
    const int*   indptr  = (const int*)  d_in[3];   // [2049] i32
    float*       y       = (float*)d_out;           // [512, 2048] f32

    tile_x<<<dim3(IN_F / 256, NTILE), 256, 0, stream>>>(x);          // 512 blocks
    spmm<<<dim3(OUT_F / ROWS, N_TOK / TPB), 256, SMEM_BYTES, stream>>>(
        data, indices, indptr, y);                                   // 512 blocks
}